// Round 1
// baseline (2941.103 us; speedup 1.0000x reference)
//
#include <hip/hip_runtime.h>

#define N_NODES 100000
#define N_EDGES 1600000
#define NFEAT 512
#define NHID 256
#define NCLASS 40
#define NPAD 100096   // 391 * 256
#define NB 391
#define CHUNK 12800

// ---------------- CSR build ----------------

__global__ void init_cnt(int* cnt) {
    int i = blockIdx.x * 256 + threadIdx.x;
    if (i < NPAD) cnt[i] = 0;
}

__global__ void count_edges(const int* __restrict__ rows, int* __restrict__ cnt) {
    int e = blockIdx.x * 256 + threadIdx.x;
    if (e < N_EDGES) atomicAdd(&cnt[rows[e]], 1);
}

__global__ void reduce_blocks(const int* __restrict__ cnt, int* __restrict__ bsum) {
    __shared__ int sh[256];
    int t = threadIdx.x;
    sh[t] = cnt[blockIdx.x * 256 + t];
    __syncthreads();
    for (int off = 128; off > 0; off >>= 1) {
        if (t < off) sh[t] += sh[t + off];
        __syncthreads();
    }
    if (t == 0) bsum[blockIdx.x] = sh[0];
}

__global__ void scan_bsums(int* bsum) {
    __shared__ int sh[512];
    int t = threadIdx.x;
    int v = (t < NB) ? bsum[t] : 0;
    sh[t] = v;
    __syncthreads();
    for (int off = 1; off < 512; off <<= 1) {
        int x = (t >= off) ? sh[t - off] : 0;
        __syncthreads();
        sh[t] += x;
        __syncthreads();
    }
    if (t < NB) bsum[t] = sh[t] - v;  // exclusive
}

__global__ void scan_write(const int* __restrict__ cnt, const int* __restrict__ bsum,
                           int* __restrict__ rowptr, int* __restrict__ cursor,
                           float* __restrict__ dinv) {
    __shared__ int sh[256];
    int t = threadIdx.x, b = blockIdx.x;
    int i = b * 256 + t;
    int v = cnt[i];
    sh[t] = v;
    __syncthreads();
    for (int off = 1; off < 256; off <<= 1) {
        int x = (t >= off) ? sh[t - off] : 0;
        __syncthreads();
        sh[t] += x;
        __syncthreads();
    }
    int rp = bsum[b] + sh[t] - v;  // exclusive prefix
    rowptr[i] = rp;
    if (i < N_NODES) {
        cursor[i] = rp;
        dinv[i] = 1.0f / (float)(v + 1);  // +1 self-loop
    }
}

__global__ void scatter_edges(const int* __restrict__ rows, const int* __restrict__ cols,
                              int* __restrict__ cursor, int* __restrict__ colidx) {
    int e = blockIdx.x * 256 + threadIdx.x;
    if (e < N_EDGES) {
        int r = rows[e];
        int pos = atomicAdd(&cursor[r], 1);
        colidx[pos] = cols[e];
    }
}

// ---------------- fp32 GEMM-NT: C[M,N] = A[M,K] @ B[N,K]^T + bias (opt relu) ----------------

__global__ __launch_bounds__(256) void gemm_nt(const float* __restrict__ A,
                                               const float* __restrict__ B,
                                               const float* __restrict__ bias,
                                               float* __restrict__ C,
                                               int M, int N, int K, int relu) {
    __shared__ float As[16][64];
    __shared__ float Bs[16][64];
    int tid = threadIdx.x;
    int lr = tid >> 2, lk = (tid & 3) << 2;
    int tx = tid & 15, ty = tid >> 4;
    int arow = blockIdx.y * 64 + lr;
    int brow = blockIdx.x * 64 + lr;
    const float* Aptr = A + (size_t)arow * K;
    const float* Bptr = B + (size_t)brow * K;
    float acc[4][4] = {};
    for (int k0 = 0; k0 < K; k0 += 16) {
        float4 av = make_float4(0.f, 0.f, 0.f, 0.f);
        float4 bv = make_float4(0.f, 0.f, 0.f, 0.f);
        if (arow < M) av = *(const float4*)(Aptr + k0 + lk);
        if (brow < N) bv = *(const float4*)(Bptr + k0 + lk);
        As[lk + 0][lr] = av.x; As[lk + 1][lr] = av.y; As[lk + 2][lr] = av.z; As[lk + 3][lr] = av.w;
        Bs[lk + 0][lr] = bv.x; Bs[lk + 1][lr] = bv.y; Bs[lk + 2][lr] = bv.z; Bs[lk + 3][lr] = bv.w;
        __syncthreads();
#pragma unroll
        for (int kk = 0; kk < 16; kk++) {
            float4 a = *(const float4*)&As[kk][ty << 2];
            float4 b = *(const float4*)&Bs[kk][tx << 2];
            float ar[4] = {a.x, a.y, a.z, a.w};
            float br[4] = {b.x, b.y, b.z, b.w};
#pragma unroll
            for (int i = 0; i < 4; i++)
#pragma unroll
                for (int j = 0; j < 4; j++) acc[i][j] += ar[i] * br[j];
        }
        __syncthreads();
    }
    int row0 = blockIdx.y * 64 + (ty << 2);
    int col0 = blockIdx.x * 64 + (tx << 2);
#pragma unroll
    for (int i = 0; i < 4; i++) {
        int r = row0 + i;
        if (r < M) {
#pragma unroll
            for (int j = 0; j < 4; j++) {
                int c = col0 + j;
                float v = acc[i][j] + bias[c];
                if (relu) v = v > 0.f ? v : 0.f;
                C[(size_t)r * N + c] = v;
            }
        }
    }
}

// ---------------- GEMM3: C[M,40] = A[M,256] @ W[40,256]^T + bias ----------------

__global__ __launch_bounds__(256) void gemm3_k(const float* __restrict__ A,
                                               const float* __restrict__ W,
                                               const float* __restrict__ bias,
                                               float* __restrict__ C, int M) {
    __shared__ float As[16][128];
    __shared__ float Bs[16][40];
    int tid = threadIdx.x;
    int lr = tid >> 2, lk = (tid & 3) << 2;
    int row_base = blockIdx.x * 128;
    int ry = tid >> 3, cx = tid & 7;  // 32 x 8 thread grid, 4 rows x 5 cols each
    float acc[4][5] = {};
    for (int k0 = 0; k0 < 256; k0 += 16) {
        int r0 = row_base + lr, r1 = row_base + lr + 64;
        float4 a0 = make_float4(0.f, 0.f, 0.f, 0.f);
        float4 a1 = make_float4(0.f, 0.f, 0.f, 0.f);
        if (r0 < M) a0 = *(const float4*)(A + (size_t)r0 * 256 + k0 + lk);
        if (r1 < M) a1 = *(const float4*)(A + (size_t)r1 * 256 + k0 + lk);
        As[lk + 0][lr] = a0.x; As[lk + 1][lr] = a0.y; As[lk + 2][lr] = a0.z; As[lk + 3][lr] = a0.w;
        As[lk + 0][lr + 64] = a1.x; As[lk + 1][lr + 64] = a1.y;
        As[lk + 2][lr + 64] = a1.z; As[lk + 3][lr + 64] = a1.w;
        if (tid < 160) {
            int br = tid >> 2, bk = (tid & 3) << 2;
            float4 bv = *(const float4*)(W + (size_t)br * 256 + k0 + bk);
            Bs[bk + 0][br] = bv.x; Bs[bk + 1][br] = bv.y; Bs[bk + 2][br] = bv.z; Bs[bk + 3][br] = bv.w;
        }
        __syncthreads();
#pragma unroll
        for (int kk = 0; kk < 16; kk++) {
            float4 a = *(const float4*)&As[kk][ry << 2];
            float ar[4] = {a.x, a.y, a.z, a.w};
            float br[5];
#pragma unroll
            for (int j = 0; j < 5; j++) br[j] = Bs[kk][cx * 5 + j];
#pragma unroll
            for (int i = 0; i < 4; i++)
#pragma unroll
                for (int j = 0; j < 5; j++) acc[i][j] += ar[i] * br[j];
        }
        __syncthreads();
    }
    int row0 = row_base + (ry << 2);
#pragma unroll
    for (int i = 0; i < 4; i++) {
        int r = row0 + i;
        if (r < M) {
#pragma unroll
            for (int j = 0; j < 5; j++) {
                int c = cx * 5 + j;
                C[(size_t)r * 40 + c] = acc[i][j] + bias[c];
            }
        }
    }
}

// ---------------- power-iteration SpMM: out = 0.5*deginv[r]*(v[r]+sum v[c]) + 0.5*h[r] ----------------

__global__ __launch_bounds__(256) void spmm_k(const float* __restrict__ v,
                                              const float* __restrict__ h,
                                              const int* __restrict__ rowptr,
                                              const int* __restrict__ colidx,
                                              const float* __restrict__ dinv,
                                              float* __restrict__ out) {
    int r = (blockIdx.x * 256 + threadIdx.x) >> 6;  // one wave per row
    int lane = threadIdx.x & 63;
    if (r >= N_NODES) return;
    int l40 = lane < 40 ? lane : 39;
    int s = rowptr[r], e = rowptr[r + 1];
    float acc = v[(size_t)r * 40 + l40];
    for (int i = s; i < e; i++) {
        int c = colidx[i];
        acc += v[(size_t)c * 40 + l40];
    }
    if (lane < 40)
        out[(size_t)r * 40 + lane] = 0.5f * dinv[r] * acc + 0.5f * h[(size_t)r * 40 + lane];
}

// ---------------- launch ----------------

extern "C" void kernel_launch(void* const* d_in, const int* in_sizes, int n_in,
                              void* d_out, int out_size, void* d_ws, size_t ws_size,
                              hipStream_t stream) {
    const float* x  = (const float*)d_in[0];
    const int*   ei = (const int*)d_in[1];
    const float* W1 = (const float*)d_in[2];
    const float* b1 = (const float*)d_in[3];
    const float* W2 = (const float*)d_in[4];
    const float* b2 = (const float*)d_in[5];
    const float* W3 = (const float*)d_in[6];
    const float* b3 = (const float*)d_in[7];
    float* out = (float*)d_out;
    const int* rows = ei;
    const int* cols = ei + N_EDGES;

    // workspace carve
    float* hid1 = (float*)d_ws;
    float* hid2 = hid1 + (size_t)CHUNK * NHID;
    float* h    = hid2 + (size_t)CHUNK * NHID;
    float* v0   = h  + (size_t)N_NODES * NCLASS;
    float* v1   = v0 + (size_t)N_NODES * NCLASS;
    int* cnt    = (int*)(v1 + (size_t)N_NODES * NCLASS);
    int* rowptr = cnt + NPAD;
    int* cursor = rowptr + NPAD;
    int* colidx = cursor + N_NODES;
    int* bsum   = colidx + N_EDGES;
    float* dinv = (float*)(bsum + 512);

    // CSR build
    init_cnt<<<NPAD / 256, 256, 0, stream>>>(cnt);
    count_edges<<<(N_EDGES + 255) / 256, 256, 0, stream>>>(rows, cnt);
    reduce_blocks<<<NB, 256, 0, stream>>>(cnt, bsum);
    scan_bsums<<<1, 512, 0, stream>>>(bsum);
    scan_write<<<NB, 256, 0, stream>>>(cnt, bsum, rowptr, cursor, dinv);
    scatter_edges<<<(N_EDGES + 255) / 256, 256, 0, stream>>>(rows, cols, cursor, colidx);

    // MLP in row chunks
    for (int off = 0; off < N_NODES; off += CHUNK) {
        int Mc = (N_NODES - off < CHUNK) ? (N_NODES - off) : CHUNK;
        dim3 g1(NHID / 64, (Mc + 63) / 64);
        gemm_nt<<<g1, 256, 0, stream>>>(x + (size_t)off * NFEAT, W1, b1, hid1, Mc, NHID, NFEAT, 1);
        gemm_nt<<<g1, 256, 0, stream>>>(hid1, W2, b2, hid2, Mc, NHID, NHID, 1);
        gemm3_k<<<(Mc + 127) / 128, 256, 0, stream>>>(hid2, W3, b3, h + (size_t)off * NCLASS, Mc);
    }

    // 10 power iterations
    const float* src = h;
    for (int it = 0; it < 10; it++) {
        float* dst = (it == 9) ? out : ((it & 1) ? v1 : v0);
        spmm_k<<<(N_NODES + 3) / 4, 256, 0, stream>>>(src, h, rowptr, colidx, dinv, dst);
        src = dst;
    }
}

// Round 2
// 1347.687 us; speedup vs baseline: 2.1823x; 2.1823x over previous
//
#include <hip/hip_runtime.h>
#include <type_traits>

#define N_NODES 100000
#define N_EDGES 1600000
#define NFEAT 512
#define NHID 256
#define NCLASS 40
#define NPAD 100096   // 391 * 256
#define NB 391
#define CHUNK 25088   // 196 * 128

typedef __bf16 bf16;
typedef __bf16 bf16x8 __attribute__((ext_vector_type(8)));
typedef float f32x4 __attribute__((ext_vector_type(4)));

// ---------------- CSR build ----------------

__global__ void init_cnt(int* cnt) {
    int i = blockIdx.x * 256 + threadIdx.x;
    if (i < NPAD) cnt[i] = 0;
}

__global__ void count_edges(const int* __restrict__ rows, int* __restrict__ cnt) {
    int e = blockIdx.x * 256 + threadIdx.x;
    if (e < N_EDGES) atomicAdd(&cnt[rows[e]], 1);
}

__global__ void reduce_blocks(const int* __restrict__ cnt, int* __restrict__ bsum) {
    __shared__ int sh[256];
    int t = threadIdx.x;
    sh[t] = cnt[blockIdx.x * 256 + t];
    __syncthreads();
    for (int off = 128; off > 0; off >>= 1) {
        if (t < off) sh[t] += sh[t + off];
        __syncthreads();
    }
    if (t == 0) bsum[blockIdx.x] = sh[0];
}

__global__ void scan_bsums(int* bsum) {
    __shared__ int sh[512];
    int t = threadIdx.x;
    int v = (t < NB) ? bsum[t] : 0;
    sh[t] = v;
    __syncthreads();
    for (int off = 1; off < 512; off <<= 1) {
        int x = (t >= off) ? sh[t - off] : 0;
        __syncthreads();
        sh[t] += x;
        __syncthreads();
    }
    if (t < NB) bsum[t] = sh[t] - v;  // exclusive
}

__global__ void scan_write(const int* __restrict__ cnt, const int* __restrict__ bsum,
                           int* __restrict__ rowptr, int* __restrict__ cursor,
                           float* __restrict__ dinv) {
    __shared__ int sh[256];
    int t = threadIdx.x, b = blockIdx.x;
    int i = b * 256 + t;
    int v = cnt[i];
    sh[t] = v;
    __syncthreads();
    for (int off = 1; off < 256; off <<= 1) {
        int x = (t >= off) ? sh[t - off] : 0;
        __syncthreads();
        sh[t] += x;
        __syncthreads();
    }
    int rp = bsum[b] + sh[t] - v;  // exclusive prefix
    rowptr[i] = rp;
    if (i < N_NODES) {
        cursor[i] = rp;
        dinv[i] = 1.0f / (float)(v + 1);  // +1 self-loop
    }
}

__global__ void scatter_edges(const int* __restrict__ rows, const int* __restrict__ cols,
                              int* __restrict__ cursor, int* __restrict__ colidx) {
    int e = blockIdx.x * 256 + threadIdx.x;
    if (e < N_EDGES) {
        int r = rows[e];
        int pos = atomicAdd(&cursor[r], 1);
        colidx[pos] = cols[e];
    }
}

// ---------------- weight conversion ----------------

__global__ void cvt_f2b(const float* __restrict__ a, bf16* __restrict__ b, int n) {
    int i = blockIdx.x * 256 + threadIdx.x;
    if (i < n) b[i] = (bf16)a[i];
}

__global__ void pad_w3(const float* __restrict__ W3, const float* __restrict__ b3,
                       bf16* __restrict__ W3p, float* __restrict__ b3p) {
    int i = blockIdx.x * 256 + threadIdx.x;  // over 64*256
    int r = i >> 8;
    W3p[i] = (bf16)((r < NCLASS) ? W3[(size_t)r * 256 + (i & 255)] : 0.f);
    if (i < 64) b3p[i] = (i < NCLASS) ? b3[i] : 0.f;
}

// ---------------- bf16 MFMA GEMM-NT ----------------
// C[M,Nout] = A[M,K] @ B[Nout,K]^T + bias, A fp32 or bf16 (converted in staging),
// B bf16. OUTMODE 0: bf16 out. OUTMODE 1: dual fp32 [M,40] + bf16 [M,64] padded.

template <int BN, typename AT, bool RELU, int OUTMODE>
__global__ __launch_bounds__(256) void gemm_mfma(const AT* __restrict__ A,
                                                 const bf16* __restrict__ B,
                                                 const float* __restrict__ bias,
                                                 bf16* __restrict__ Cb,
                                                 float* __restrict__ Cf,
                                                 bf16* __restrict__ Cpad,
                                                 int M, int K, int Nout) {
    constexpr int LDT = 56;                      // padded LDS row (bf16), 112 B: 16B-aligned, 2-way banks
    constexpr int WTM = (BN == 128) ? 64 : 32;   // wave tile M
    constexpr int MI = WTM / 16;
    constexpr int WMC = 128 / WTM;               // waves along M
    __shared__ bf16 As[128 * LDT];
    __shared__ bf16 Bs[BN * LDT];

    int tid = threadIdx.x;
    int wave = tid >> 6, lane = tid & 63;
    int waveM = wave % WMC, waveN = wave / WMC;
    int lc = lane & 15, lq = lane >> 4;

    f32x4 acc[MI][4];
#pragma unroll
    for (int i = 0; i < MI; i++)
#pragma unroll
        for (int j = 0; j < 4; j++) acc[i][j] = (f32x4){0.f, 0.f, 0.f, 0.f};

    int sr = tid >> 2;           // staging row base
    int sc = (tid & 3) * 8;      // staging col (8 bf16)

    for (int k0 = 0; k0 < K; k0 += 32) {
        // stage A: 128 x 32
#pragma unroll
        for (int g = 0; g < 2; g++) {
            int r = sr + g * 64;
            int grow = blockIdx.y * 128 + r;
            bf16x8 val = (bf16x8){};
            if (grow < M) {
                if constexpr (std::is_same<AT, float>::value) {
                    const float* ap = A + (size_t)grow * K + k0 + sc;
                    float4 p0 = *(const float4*)ap;
                    float4 p1 = *(const float4*)(ap + 4);
                    val[0] = (bf16)p0.x; val[1] = (bf16)p0.y; val[2] = (bf16)p0.z; val[3] = (bf16)p0.w;
                    val[4] = (bf16)p1.x; val[5] = (bf16)p1.y; val[6] = (bf16)p1.z; val[7] = (bf16)p1.w;
                } else {
                    val = *(const bf16x8*)(A + (size_t)grow * K + k0 + sc);
                }
            }
            *(bf16x8*)&As[r * LDT + sc] = val;
        }
        // stage B: BN x 32 (N dims always exact multiples; no bounds)
#pragma unroll
        for (int g = 0; g < BN / 64; g++) {
            int r = sr + g * 64;
            int brow = blockIdx.x * BN + r;
            *(bf16x8*)&Bs[r * LDT + sc] = *(const bf16x8*)(B + (size_t)brow * K + k0 + sc);
        }
        __syncthreads();

        bf16x8 af[MI], bf[4];
#pragma unroll
        for (int i = 0; i < MI; i++)
            af[i] = *(const bf16x8*)&As[(waveM * WTM + i * 16 + lc) * LDT + lq * 8];
#pragma unroll
        for (int j = 0; j < 4; j++)
            bf[j] = *(const bf16x8*)&Bs[(waveN * 64 + j * 16 + lc) * LDT + lq * 8];
#pragma unroll
        for (int i = 0; i < MI; i++)
#pragma unroll
            for (int j = 0; j < 4; j++)
                acc[i][j] = __builtin_amdgcn_mfma_f32_16x16x32_bf16(af[i], bf[j], acc[i][j], 0, 0, 0);
        __syncthreads();
    }

    // epilogue
#pragma unroll
    for (int i = 0; i < MI; i++) {
        int row0 = blockIdx.y * 128 + waveM * WTM + i * 16 + lq * 4;
#pragma unroll
        for (int j = 0; j < 4; j++) {
            int colL = waveN * 64 + j * 16 + lc;
            int col = blockIdx.x * BN + colL;
            float bv = bias[col];
#pragma unroll
            for (int reg = 0; reg < 4; reg++) {
                int rr = row0 + reg;
                if (rr < M) {
                    float v = acc[i][j][reg] + bv;
                    if (RELU) v = v > 0.f ? v : 0.f;
                    if (OUTMODE == 0) {
                        Cb[(size_t)rr * Nout + col] = (bf16)v;
                    } else {
                        if (col < NCLASS) Cf[(size_t)rr * NCLASS + col] = v;
                        Cpad[(size_t)rr * 64 + col] = (bf16)v;
                    }
                }
            }
        }
    }
}

// ---------------- power-iteration SpMM (bf16 v padded to 64) ----------------

__global__ __launch_bounds__(256) void spmm_b(const bf16* __restrict__ v,
                                              const float* __restrict__ h,
                                              const int* __restrict__ rowptr,
                                              const int* __restrict__ colidx,
                                              const float* __restrict__ dinv,
                                              bf16* __restrict__ outB,
                                              float* __restrict__ outF,
                                              int final_it) {
    int r = (blockIdx.x * 256 + threadIdx.x) >> 6;  // one wave per row
    int lane = threadIdx.x & 63;
    if (r >= N_NODES || lane >= NCLASS) return;
    int s = rowptr[r], e = rowptr[r + 1];
    float a0 = (float)v[(size_t)r * 64 + lane];  // self-loop
    float a1 = 0.f, a2 = 0.f, a3 = 0.f;
    int i = s;
    for (; i + 4 <= e; i += 4) {
        int c0 = colidx[i], c1 = colidx[i + 1], c2 = colidx[i + 2], c3 = colidx[i + 3];
        a0 += (float)v[(size_t)c0 * 64 + lane];
        a1 += (float)v[(size_t)c1 * 64 + lane];
        a2 += (float)v[(size_t)c2 * 64 + lane];
        a3 += (float)v[(size_t)c3 * 64 + lane];
    }
    for (; i < e; i++) a0 += (float)v[(size_t)colidx[i] * 64 + lane];
    float res = 0.5f * dinv[r] * ((a0 + a1) + (a2 + a3)) + 0.5f * h[(size_t)r * NCLASS + lane];
    if (final_it) outF[(size_t)r * NCLASS + lane] = res;
    else outB[(size_t)r * 64 + lane] = (bf16)res;
}

// ---------------- launch ----------------

extern "C" void kernel_launch(void* const* d_in, const int* in_sizes, int n_in,
                              void* d_out, int out_size, void* d_ws, size_t ws_size,
                              hipStream_t stream) {
    const float* x  = (const float*)d_in[0];
    const int*   ei = (const int*)d_in[1];
    const float* W1 = (const float*)d_in[2];
    const float* b1 = (const float*)d_in[3];
    const float* W2 = (const float*)d_in[4];
    const float* b2 = (const float*)d_in[5];
    const float* W3 = (const float*)d_in[6];
    const float* b3 = (const float*)d_in[7];
    float* out = (float*)d_out;
    const int* rows = ei;
    const int* cols = ei + N_EDGES;

    // workspace carve (bytes)
    char* p = (char*)d_ws;
    bf16* hid1 = (bf16*)p;                 p += (size_t)CHUNK * NHID * 2;     // 12.85 MB (later: v0)
    bf16* hid2 = (bf16*)p;                 p += (size_t)CHUNK * NHID * 2;     // 12.85 MB (later: v1)
    float* h   = (float*)p;                p += (size_t)N_NODES * NCLASS * 4; // 16 MB
    bf16* hpad = (bf16*)p;                 p += (size_t)N_NODES * 64 * 2;     // 12.8 MB
    bf16* W1b  = (bf16*)p;                 p += (size_t)NHID * NFEAT * 2;
    bf16* W2b  = (bf16*)p;                 p += (size_t)NHID * NHID * 2;
    bf16* W3p  = (bf16*)p;                 p += (size_t)64 * NHID * 2;
    float* b3p = (float*)p;                p += 64 * 4;
    int* cnt    = (int*)p;                 p += (size_t)NPAD * 4;
    int* rowptr = (int*)p;                 p += (size_t)(NPAD + 1) * 4;
    int* cursor = (int*)p;                 p += (size_t)N_NODES * 4;
    int* colidx = (int*)p;                 p += (size_t)N_EDGES * 4;
    int* bsum   = (int*)p;                 p += 512 * 4;
    float* dinv = (float*)p;               p += (size_t)N_NODES * 4;
    // v0/v1 alias hid1/hid2 (dead after MLP finishes)
    bf16* v0 = hid1;
    bf16* v1 = hid2;

    // CSR build
    init_cnt<<<NPAD / 256, 256, 0, stream>>>(cnt);
    count_edges<<<(N_EDGES + 255) / 256, 256, 0, stream>>>(rows, cnt);
    reduce_blocks<<<NB, 256, 0, stream>>>(cnt, bsum);
    scan_bsums<<<1, 512, 0, stream>>>(bsum);
    scan_write<<<NB, 256, 0, stream>>>(cnt, bsum, rowptr, cursor, dinv);
    scatter_edges<<<(N_EDGES + 255) / 256, 256, 0, stream>>>(rows, cols, cursor, colidx);

    // weight conversion
    cvt_f2b<<<(NHID * NFEAT + 255) / 256, 256, 0, stream>>>(W1, W1b, NHID * NFEAT);
    cvt_f2b<<<(NHID * NHID + 255) / 256, 256, 0, stream>>>(W2, W2b, NHID * NHID);
    pad_w3<<<(64 * NHID) / 256, 256, 0, stream>>>(W3, b3, W3p, b3p);

    // MLP in row chunks
    for (int off = 0; off < N_NODES; off += CHUNK) {
        int Mc = (N_NODES - off < CHUNK) ? (N_NODES - off) : CHUNK;
        int gy = (Mc + 127) / 128;
        dim3 g12(2, gy);
        gemm_mfma<128, float, true, 0><<<g12, 256, 0, stream>>>(
            x + (size_t)off * NFEAT, W1b, b1, hid1, nullptr, nullptr, Mc, NFEAT, NHID);
        gemm_mfma<128, bf16, true, 0><<<g12, 256, 0, stream>>>(
            hid1, W2b, b2, hid2, nullptr, nullptr, Mc, NHID, NHID);
        dim3 g3(1, gy);
        gemm_mfma<64, bf16, false, 1><<<g3, 256, 0, stream>>>(
            hid2, W3p, b3p, nullptr, h + (size_t)off * NCLASS, hpad + (size_t)off * 64,
            Mc, NHID, 64);
    }

    // 10 power iterations (v stored bf16, rows padded to 64 = one 128B line)
    const bf16* src = hpad;
    for (int it = 0; it < 10; it++) {
        int fin = (it == 9);
        bf16* dst = (it & 1) ? v1 : v0;
        spmm_b<<<(N_NODES * 64 + 255) / 256, 256, 0, stream>>>(
            src, h, rowptr, colidx, dinv, dst, out, fin);
        src = dst;
    }
}